// Round 6
// baseline (460.745 us; speedup 1.0000x reference)
//
#include <hip/hip_runtime.h>
#include <hip/hip_bf16.h>
#include <math.h>

// Problem constants (B=4096 rows, D=768 features)
#define B_ROWS 4096
#define D_DIM  768

#define WT 64              // wave tile: 64x64 output per single-wave block
#define BK 64              // K-slab: 64 bf16 = 128 B per row = 8 x 16B chunks
#define NKT (D_DIM / BK)   // 12 K-slabs
#define NTIL (B_ROWS / WT) // 64 tiles per dim
#define GRID_TILES (NTIL * NTIL)   // 4096 single-wave blocks

typedef __attribute__((ext_vector_type(8))) short bf16x8;  // 8 bf16 = 4 VGPRs (MFMA A/B frag)
typedef __attribute__((ext_vector_type(4))) float f32x4;   // MFMA C/D frag

__device__ __forceinline__ unsigned short f32_to_bf16(float x) {
    // round-to-nearest-even; inputs are finite normals
    unsigned int u = __float_as_uint(x);
    return (unsigned short)((u + 0x7fffu + ((u >> 16) & 1u)) >> 16);
}

// K1: per-row stats + fp32->bf16 conversion. One WAVE per row (4 rows/block).
__global__ void __launch_bounds__(256) rowstats_kernel(
    const float* __restrict__ P, const float* __restrict__ T,
    unsigned short* __restrict__ Pb, unsigned short* __restrict__ Tb,
    float* __restrict__ p_sq, float* __restrict__ t_sq,
    float* __restrict__ diagl, float* __restrict__ magr,
    float* __restrict__ rowsum, unsigned int* __restrict__ counter)
{
    if (blockIdx.x == 0 && threadIdx.x == 0) *counter = 0u;
    const int wave = threadIdx.x >> 6, lane = threadIdx.x & 63;
    const int i = blockIdx.x * 4 + wave;
    const f32x4* prow = (const f32x4*)(P + (size_t)i * D_DIM);
    const f32x4* trow = (const f32x4*)(T + (size_t)i * D_DIM);
    ushort4* pbrow = (ushort4*)(Pb + (size_t)i * D_DIM);
    ushort4* tbrow = (ushort4*)(Tb + (size_t)i * D_DIM);

    float psq = 0.f, tsq = 0.f, cr = 0.f, l1 = 0.f, tm = 0.f;
    #pragma unroll
    for (int u = 0; u < 3; ++u) {         // 192 float4 per row / 64 lanes
        const int c4 = u * 64 + lane;
        f32x4 p = prow[c4], t = trow[c4];
        #pragma unroll
        for (int k = 0; k < 4; ++k) {
            psq += p[k] * p[k]; tsq += t[k] * t[k]; cr += p[k] * t[k];
            l1 += fabsf(p[k] - t[k]); tm += fabsf(t[k]);
        }
        pbrow[c4] = make_ushort4(f32_to_bf16(p[0]), f32_to_bf16(p[1]),
                                 f32_to_bf16(p[2]), f32_to_bf16(p[3]));
        tbrow[c4] = make_ushort4(f32_to_bf16(t[0]), f32_to_bf16(t[1]),
                                 f32_to_bf16(t[2]), f32_to_bf16(t[3]));
    }
    #pragma unroll
    for (int m = 1; m < 64; m <<= 1) {
        psq += __shfl_xor(psq, m, 64);
        tsq += __shfl_xor(tsq, m, 64);
        cr  += __shfl_xor(cr,  m, 64);
        l1  += __shfl_xor(l1,  m, 64);
        tm  += __shfl_xor(tm,  m, 64);
    }
    if (lane == 0) {
        p_sq[i] = psq;
        t_sq[i] = tsq;
        float sq = fmaxf(psq + tsq - 2.0f * cr, 0.0f);
        diagl[i] = -sqrtf(sq) * 10.0f;    // logit_ii = -dist/0.1 (the LSE shift)
        magr[i]  = l1 / tm;
        rowsum[i] = 0.0f;
    }
}

// K2: BARRIER-FREE bf16-MFMA cross GEMM. One wave per block, 64x64 output
// tile, wave-private 16 KB LDS -> no __syncthreads in the K-loop at all.
//
// R3/R4/R5 lesson: __syncthreads always emits s_waitcnt vmcnt(0) (m97 asm),
// so ANY shared-tile structure exposes the full global-fetch latency every
// K-iter. With a wave-private tile the producer-consumer chain
// (global->VGPR -> ds_write -> ds_read -> MFMA) is ordered only by
// fine-grained vmcnt/lgkmcnt, which the compiler emits precisely — next
// slab's 16 loads stay in flight through the entire MFMA phase.
//
// Cost: A/B each fetched 64x (806 MB L2->CU). XCD swizzle keeps each 16x16
// tile group's 3 MB window inside one XCD's 4 MB L2.
// LDS chunk-XOR swizzle (slot = chunk ^ row&7): 0 bank conflicts (R2-R5).
__global__ void __launch_bounds__(64, 2) lse_gemm_kernel(
    const unsigned short* __restrict__ Pb, const unsigned short* __restrict__ Tb,
    const float* __restrict__ p_sq, const float* __restrict__ t_sq,
    const float* __restrict__ diagl, const float* __restrict__ magr,
    float* __restrict__ rowsum, unsigned int* __restrict__ counter,
    float* __restrict__ out)
{
    __shared__ __align__(16) unsigned short As[WT * BK];  // 8 KB, wave-private
    __shared__ __align__(16) unsigned short Bs[WT * BK];  // 8 KB

    const int lane = threadIdx.x;     // single 64-lane wave

    // XCD swizzle: HW round-robins wg id over 8 XCDs (flat%8). 16x16 tile
    // groups (1024x1024 window = 3 MB bf16 < 4 MiB L2); 2 groups per XCD.
    const int flat = blockIdx.x;
    const int xcd  = flat & 7;
    const int s    = flat >> 3;                 // 0..511 slot within XCD
    const int g    = xcd * 2 + (s >> 8);        // group 0..15
    const int w    = s & 255;                   // tile within 16x16 group
    const int i0   = (((g >> 2) << 4) + (w >> 4)) * WT;  // P row block
    const int j0   = (((g & 3) << 4) + (w & 15)) * WT;   // T row block

    const int row16 = lane & 15, quad = lane >> 4;
    const int swz = (quad ^ (row16 & 7)) << 4;  // ds_read swizzled byte offset

    // staging map: lane covers rows lr+8q (q=0..7), chunk cr (16B) per row;
    // LDS slot = cr ^ (row&7) = cr ^ lr (q*8 doesn't change row&7).
    const int lr = lane >> 3;          // base row 0..7
    const int cr = lane & 7;           // chunk in row
    const int sw = cr ^ lr;            // swizzled slot
    const int4* gA = (const int4*)Pb + (size_t)(i0 + lr) * (D_DIM / 8) + cr;
    const int4* gB = (const int4*)Tb + (size_t)(j0 + lr) * (D_DIM / 8) + cr;
    int4* lwA = (int4*)As + lr * 8 + sw;   // +q*64 int4 per 8-row step
    int4* lwB = (int4*)Bs + lr * 8 + sw;

    f32x4 acc[4][4];
    #pragma unroll
    for (int a = 0; a < 4; ++a)
        #pragma unroll
        for (int b = 0; b < 4; ++b)
            acc[a][b] = (f32x4){0.f, 0.f, 0.f, 0.f};

    // prologue: slab 0 -> regs (16 loads in flight)
    int4 stA[8], stB[8];
    #pragma unroll
    for (int q = 0; q < 8; ++q) {
        stA[q] = gA[q * 768];          // 8 rows * 96 int4/row
        stB[q] = gB[q * 768];
    }

    const char* Ab = (const char*)As;
    const char* Bb = (const char*)Bs;

    for (int kt = 0; kt < NKT; ++kt) {
        // regs -> private LDS (compiler waits vmcnt per-write, fine-grained)
        #pragma unroll
        for (int q = 0; q < 8; ++q) {
            lwA[q * 64] = stA[q];
            lwB[q * 64] = stB[q];
        }
        if (kt + 1 < NKT) {            // issue next slab NOW; in flight
            const int ko = (kt + 1) * 8;   // through the whole MFMA phase
            #pragma unroll
            for (int q = 0; q < 8; ++q) {
                stA[q] = gA[q * 768 + ko];
                stB[q] = gB[q * 768 + ko];
            }
        }
        // no barrier: same wave wrote the LDS it reads (lgkmcnt orders it)
        #pragma unroll
        for (int ks = 0; ks < BK; ks += 32) {
            const int kx = ks ? 64 : 0;   // chunk+4 == slot^4 == byte addr^64
            bf16x8 a[4], b[4];
            #pragma unroll
            for (int mt = 0; mt < 4; ++mt)
                a[mt] = *(const bf16x8*)(Ab + (((mt * 16 + row16) * 128 + swz) ^ kx));
            #pragma unroll
            for (int nt = 0; nt < 4; ++nt)
                b[nt] = *(const bf16x8*)(Bb + (((nt * 16 + row16) * 128 + swz) ^ kx));
            #pragma unroll
            for (int mt = 0; mt < 4; ++mt)
                #pragma unroll
                for (int nt = 0; nt < 4; ++nt)
                    acc[mt][nt] = __builtin_amdgcn_mfma_f32_16x16x32_bf16(
                        a[mt], b[nt], acc[mt][nt], 0, 0, 0);
        }
    }

    // Epilogue: C/D layout col=lane&15, row=quad*4+reg (m89/m91-verified).
    // term = exp(logit_ij - logit_ii) via exp2f; max shifted log2-exp ~99 < 127.
    const float NT_LOG2E = -14.4269504089f;   // -(1/TEMP) * log2(e)
    const float LOG2E    = 1.44269504089f;
    float tsq_l[4];
    #pragma unroll
    for (int nt = 0; nt < 4; ++nt)
        tsq_l[nt] = t_sq[j0 + nt * 16 + row16];

    #pragma unroll
    for (int mt = 0; mt < 4; ++mt) {
        #pragma unroll
        for (int r = 0; r < 4; ++r) {
            const int i = i0 + mt * 16 + quad * 4 + r;
            const float psq = p_sq[i];
            const float c0  = -diagl[i] * LOG2E;  // -logit_ii in log2 domain
            float sfin = 0.f;
            #pragma unroll
            for (int nt = 0; nt < 4; ++nt) {
                float c  = acc[mt][nt][r];
                float sq = fmaxf(fmaf(-2.0f, c, psq + tsq_l[nt]), 0.0f);
                float d  = sqrtf(sq);
                float y  = fmaf(d, NT_LOG2E, c0);  // (logit-logit_ii)*log2e
                sfin += exp2f(y);
            }
            #pragma unroll
            for (int m = 1; m < 16; m <<= 1) sfin += __shfl_xor(sfin, m, 64);
            if (row16 == 0) atomicAdd(&rowsum[i], sfin);
        }
    }

    // Fused finalize: last block reduces rowsum -> 3 scalars. rowsum is only
    // touched by device-scope atomics (adds above, reads via atomicAdd(p,0)).
    __threadfence();
    unsigned int old = 0u;
    if (lane == 0) old = atomicAdd(counter, 1u);
    old = (unsigned int)__shfl((int)old, 0, 64);
    if (old == (unsigned)(GRID_TILES - 1)) {
        double sc = 0.0, sm = 0.0;
        for (int i = lane; i < B_ROWS; i += 64) {
            float rs = atomicAdd(&rowsum[i], 0.0f);   // coherent read
            sc += (double)logf(rs);   // logf + double sum: abs err ~1e-5, fine
            sm += (double)magr[i];
        }
        #pragma unroll
        for (int m = 1; m < 64; m <<= 1) {
            sc += __shfl_xor(sc, m, 64);
            sm += __shfl_xor(sm, m, 64);
        }
        if (lane == 0) {
            double lc = sc / (double)B_ROWS;
            double lm = sm / (double)B_ROWS;
            out[0] = (float)(0.5 * lc + 0.5 * lm);  // LOSS_SCALE=1, LAMBD=0.5
            out[1] = (float)lc;
            out[2] = (float)lm;
        }
    }
}

extern "C" void kernel_launch(void* const* d_in, const int* in_sizes, int n_in,
                              void* d_out, int out_size, void* d_ws, size_t ws_size,
                              hipStream_t stream) {
    const float* P = (const float*)d_in[0];   // predicted [4096,768] fp32
    const float* T = (const float*)d_in[1];   // target    [4096,768] fp32
    float* out = (float*)d_out;               // 3 fp32 scalars

    char* ws = (char*)d_ws;
    float* rowsum = (float*)ws;               ws += B_ROWS * sizeof(float);
    float* p_sq   = (float*)ws;               ws += B_ROWS * sizeof(float);
    float* t_sq   = (float*)ws;               ws += B_ROWS * sizeof(float);
    float* diagl  = (float*)ws;               ws += B_ROWS * sizeof(float);
    float* magr   = (float*)ws;               ws += B_ROWS * sizeof(float);
    unsigned int* counter = (unsigned int*)ws; ws += 16;  // keep 16B align
    unsigned short* Pb = (unsigned short*)ws; ws += (size_t)B_ROWS * D_DIM * 2;
    unsigned short* Tb = (unsigned short*)ws;

    rowstats_kernel<<<B_ROWS / 4, 256, 0, stream>>>(
        P, T, Pb, Tb, p_sq, t_sq, diagl, magr, rowsum, counter);
    lse_gemm_kernel<<<GRID_TILES, 64, 0, stream>>>(
        Pb, Tb, p_sq, t_sq, diagl, magr, rowsum, counter, out);
}

// Round 7
// 186.825 us; speedup vs baseline: 2.4662x; 2.4662x over previous
//
#include <hip/hip_runtime.h>
#include <hip/hip_bf16.h>
#include <math.h>

// Problem constants (B=4096 rows, D=768 features)
#define B_ROWS 4096
#define D_DIM  768
#define NK8    (D_DIM / 8)      // 96 chunks of 8 bf16 along K

#define NBLK   32               // 128x128 block tiles per dim (4 waves of 64x64)
#define GRID_TILES (NBLK * NBLK)

typedef __attribute__((ext_vector_type(8)))  short bf16x8;   // MFMA A/B frag (4 VGPRs)
typedef __attribute__((ext_vector_type(16))) float f32x16;   // 32x32 MFMA C/D frag
typedef __attribute__((ext_vector_type(4)))  float f32x4;

__device__ __forceinline__ unsigned short f32_to_bf16(float x) {
    unsigned int u = __float_as_uint(x);   // RNE; inputs finite
    return (unsigned short)((u + 0x7fffu + ((u >> 16) & 1u)) >> 16);
}

// K1 "prep": per-row stats + fp32->bf16 + transpose to K-major chunk layout:
//   Pk[k8*4096 + i] = 16B = 8 bf16 of row i, k = k8*8..+8.
// This makes the 32x32x16 MFMA A/B fragment (lane L -> row L&31, chunk L>>5)
// a perfectly coalesced direct-global load: NO LDS in the GEMM K-loop.
// Block: 16 rows x 768 cols; thread (r = tid&15, c16 = tid>>4) covers 16 cols
// per iter (64B read granule, coalesced 512B-per-k8 writes).
__global__ void __launch_bounds__(256) prep_kernel(
    const float* __restrict__ P, const float* __restrict__ T,
    int4* __restrict__ Pk, int4* __restrict__ Tk,
    float* __restrict__ p_sq, float* __restrict__ t_sq,
    float* __restrict__ diagl, float* __restrict__ magr,
    float* __restrict__ rowsum, unsigned int* __restrict__ counter)
{
    const int tid = threadIdx.x;
    if (blockIdx.x == 0 && tid == 0) *counter = 0u;
    const int r   = tid & 15;
    const int c16 = tid >> 4;            // 0..15
    const int i0  = blockIdx.x * 16;
    const int i   = i0 + r;

    const float* prow = P + (size_t)i * D_DIM;
    const float* trow = T + (size_t)i * D_DIM;

    float psq = 0.f, tsq = 0.f, cr = 0.f, l1 = 0.f, tmag = 0.f;
    #pragma unroll
    for (int it = 0; it < 3; ++it) {     // 3 x 256 cols
        const int cb = it * 256 + c16 * 16;
        const f32x4* pp = (const f32x4*)(prow + cb);
        const f32x4* tp = (const f32x4*)(trow + cb);
        f32x4 pv[4], tv[4];
        #pragma unroll
        for (int q = 0; q < 4; ++q) { pv[q] = pp[q]; tv[q] = tp[q]; }
        #pragma unroll
        for (int q = 0; q < 4; ++q)
            #pragma unroll
            for (int k = 0; k < 4; ++k) {
                float p = pv[q][k], t = tv[q][k];
                psq += p * p; tsq += t * t; cr += p * t;
                l1 += fabsf(p - t); tmag += fabsf(t);
            }
        // pack two 8-elem chunks each for P and T, store K-major
        #pragma unroll
        for (int half = 0; half < 2; ++half) {
            union { unsigned short u[8]; int4 v; } up, ut;
            #pragma unroll
            for (int e = 0; e < 8; ++e) {
                up.u[e] = f32_to_bf16(pv[half * 2 + (e >> 2)][e & 3]);
                ut.u[e] = f32_to_bf16(tv[half * 2 + (e >> 2)][e & 3]);
            }
            const int k8 = (cb >> 3) + half;
            Pk[(size_t)k8 * B_ROWS + i] = up.v;
            Tk[(size_t)k8 * B_ROWS + i] = ut.v;
        }
    }
    // combine 16 partial stats per row via LDS atomics
    __shared__ float red[16][5];
    if (tid < 16) {
        #pragma unroll
        for (int k = 0; k < 5; ++k) red[tid][k] = 0.f;
    }
    __syncthreads();
    atomicAdd(&red[r][0], psq);  atomicAdd(&red[r][1], tsq);
    atomicAdd(&red[r][2], cr);   atomicAdd(&red[r][3], l1);
    atomicAdd(&red[r][4], tmag);
    __syncthreads();
    if (tid < 16) {
        const int ii = i0 + tid;
        float a = red[tid][0], b = red[tid][1], c = red[tid][2];
        p_sq[ii] = a;
        t_sq[ii] = b;
        float sq = fmaxf(a + b - 2.0f * c, 0.0f);
        diagl[ii] = -sqrtf(sq) * 10.0f;   // logit_ii = -dist/0.1 (LSE shift)
        magr[ii]  = red[tid][3] / red[tid][4];
        rowsum[ii] = 0.0f;
    }
}

// K2: LDS-FREE bf16-MFMA cross GEMM + shifted-exp row-sum + fused finalize.
//
// R2-R6 lesson chain: the 57-60us plateau was LDS-pipe-bound (per-CU LDS
// demand ~3072cyc/iter vs 600cyc MFMA -> 19% MfmaUtil ceiling, matching
// measurement), and every VGPR-staging variant got spilled to scratch by the
// allocator (R4/R5/R6: WRITE_SIZE 284-790MB). Fix: K-major layout makes MFMA
// fragments directly loadable from global (coalesced 2x512B per instr);
// loads are consumed in the same unrolled k-step (no loop-carried staging,
// no LDS, no barriers). L2 feeds ~786MB at ~30TB/s; L1 absorbs intra-block
// duplicate reads (waves in the 2x2 grid pairwise share A- or B-windows).
//
// Wave tile 64x64 = 2x2 of mfma_f32_32x32x16_bf16.
// C/D layout (m74/m101-verified): col=lane&31, row=(reg&3)+8*(reg>>2)+4*(lane>>5).
__global__ void __launch_bounds__(256, 2) lse_gemm_kernel(
    const int4* __restrict__ Pk, const int4* __restrict__ Tk,
    const float* __restrict__ p_sq, const float* __restrict__ t_sq,
    const float* __restrict__ diagl, const float* __restrict__ magr,
    float* __restrict__ rowsum, unsigned int* __restrict__ counter,
    float* __restrict__ out)
{
    const int tid  = threadIdx.x;
    const int lane = tid & 63;
    const int wave = tid >> 6;
    const int wm = wave >> 1, wn = wave & 1;     // 2x2 wave grid in 128x128 block
    const int h  = lane >> 5, l5 = lane & 31;

    // XCD swizzle: 8x8 block groups (1024x1024 window ~3MB bf16 < 4MiB L2)
    const int flat = blockIdx.x;
    const int xcd  = flat & 7;
    const int s    = flat >> 3;                  // 0..127
    const int g    = xcd * 2 + (s >> 6);         // group 0..15
    const int w    = s & 63;
    const int i0   = ((((g >> 2) << 3) + (w >> 3)) << 7) + wm * 64;  // wave's P rows
    const int j0   = ((((g & 3) << 3) + (w & 7)) << 7) + wn * 64;    // wave's T rows

    const bf16x8* A = (const bf16x8*)Pk;   // idx = k8*4096 + row
    const bf16x8* Bm = (const bf16x8*)Tk;

    f32x16 acc00, acc01, acc10, acc11;
    #pragma unroll
    for (int e = 0; e < 16; ++e) { acc00[e]=0.f; acc01[e]=0.f; acc10[e]=0.f; acc11[e]=0.f; }

    const int ia = i0 + l5, ja = j0 + l5;
    int idx = h * B_ROWS;                  // k8 = 2*ks + h
    #pragma unroll 4
    for (int ks = 0; ks < 48; ++ks) {      // 48 steps of K=16
        bf16x8 a0 = A[idx + ia];
        bf16x8 a1 = A[idx + ia + 32];
        bf16x8 b0 = Bm[idx + ja];
        bf16x8 b1 = Bm[idx + ja + 32];
        acc00 = __builtin_amdgcn_mfma_f32_32x32x16_bf16(a0, b0, acc00, 0, 0, 0);
        acc01 = __builtin_amdgcn_mfma_f32_32x32x16_bf16(a0, b1, acc01, 0, 0, 0);
        acc10 = __builtin_amdgcn_mfma_f32_32x32x16_bf16(a1, b0, acc10, 0, 0, 0);
        acc11 = __builtin_amdgcn_mfma_f32_32x32x16_bf16(a1, b1, acc11, 0, 0, 0);
        idx += 2 * B_ROWS;
    }

    // Epilogue: term = exp(logit_ij - logit_ii) via exp2f (max log2-exp ~99 < 127)
    const float NT_LOG2E = -14.4269504089f;   // -(1/TEMP) * log2(e)
    const float LOG2E    = 1.44269504089f;
    const float pv  = p_sq[i0 + lane];        // rows i0..i0+63 held across lanes
    const float dv  = diagl[i0 + lane];
    const float tq0 = t_sq[j0 + l5];
    const float tq1 = t_sq[j0 + 32 + l5];

    #pragma unroll
    for (int tm = 0; tm < 2; ++tm) {
        const f32x16& C0 = tm ? acc10 : acc00;
        const f32x16& C1 = tm ? acc11 : acc01;
        #pragma unroll
        for (int r = 0; r < 16; ++r) {
            const int rr = tm * 32 + (r & 3) + 8 * (r >> 2) + 4 * h;  // 0..63
            const float psq = __shfl(pv, rr, 64);
            const float c0  = -__shfl(dv, rr, 64) * LOG2E;
            float c  = C0[r];
            float sq = fmaxf(fmaf(-2.0f, c, psq + tq0), 0.0f);
            float sm = exp2f(fmaf(sqrtf(sq), NT_LOG2E, c0));
            c  = C1[r];
            sq = fmaxf(fmaf(-2.0f, c, psq + tq1), 0.0f);
            sm += exp2f(fmaf(sqrtf(sq), NT_LOG2E, c0));
            // reduce across the 32 lanes of this half (masks < 32 stay in-half)
            #pragma unroll
            for (int m = 1; m < 32; m <<= 1) sm += __shfl_xor(sm, m, 64);
            if (l5 == 0) atomicAdd(&rowsum[i0 + rr], sm);
        }
    }

    // Fused finalize: last block reduces rowsum -> 3 scalars (rowsum only ever
    // touched by device-scope atomics; reads via atomicAdd(p,0) are coherent).
    __threadfence();
    __shared__ unsigned int lastflag;
    if (tid == 0) {
        unsigned int old = atomicAdd(counter, 1u);
        lastflag = (old == (unsigned)(GRID_TILES - 1)) ? 1u : 0u;
    }
    __syncthreads();
    if (lastflag) {
        double sc = 0.0, smg = 0.0;
        for (int i = tid; i < B_ROWS; i += 256) {
            float rs = atomicAdd(&rowsum[i], 0.0f);
            sc += (double)logf(rs);
            smg += (double)magr[i];
        }
        #pragma unroll
        for (int m = 1; m < 64; m <<= 1) {
            sc  += __shfl_xor(sc,  m, 64);
            smg += __shfl_xor(smg, m, 64);
        }
        __shared__ double red2[4][2];
        if ((tid & 63) == 0) { red2[tid >> 6][0] = sc; red2[tid >> 6][1] = smg; }
        __syncthreads();
        if (tid == 0) {
            sc  = red2[0][0] + red2[1][0] + red2[2][0] + red2[3][0];
            smg = red2[0][1] + red2[1][1] + red2[2][1] + red2[3][1];
            double lc = sc / (double)B_ROWS;
            double lm = smg / (double)B_ROWS;
            out[0] = (float)(0.5 * lc + 0.5 * lm);  // LOSS_SCALE=1, LAMBD=0.5
            out[1] = (float)lc;
            out[2] = (float)lm;
        }
    }
}

extern "C" void kernel_launch(void* const* d_in, const int* in_sizes, int n_in,
                              void* d_out, int out_size, void* d_ws, size_t ws_size,
                              hipStream_t stream) {
    const float* P = (const float*)d_in[0];   // predicted [4096,768] fp32
    const float* T = (const float*)d_in[1];   // target    [4096,768] fp32
    float* out = (float*)d_out;               // 3 fp32 scalars

    char* ws = (char*)d_ws;
    float* rowsum = (float*)ws;               ws += B_ROWS * sizeof(float);
    float* p_sq   = (float*)ws;               ws += B_ROWS * sizeof(float);
    float* t_sq   = (float*)ws;               ws += B_ROWS * sizeof(float);
    float* diagl  = (float*)ws;               ws += B_ROWS * sizeof(float);
    float* magr   = (float*)ws;               ws += B_ROWS * sizeof(float);
    unsigned int* counter = (unsigned int*)ws; ws += 16;  // keep 16B align
    int4* Pk = (int4*)ws;                     ws += (size_t)B_ROWS * D_DIM * 2;
    int4* Tk = (int4*)ws;

    prep_kernel<<<B_ROWS / 16, 256, 0, stream>>>(
        P, T, Pk, Tk, p_sq, t_sq, diagl, magr, rowsum, counter);
    lse_gemm_kernel<<<GRID_TILES, 256, 0, stream>>>(
        Pk, Tk, p_sq, t_sq, diagl, magr, rowsum, counter, out);
}

// Round 8
// 146.745 us; speedup vs baseline: 3.1398x; 1.2731x over previous
//
#include <hip/hip_runtime.h>
#include <hip/hip_bf16.h>
#include <math.h>

// Problem constants (B=4096 rows, D=768 features)
#define B_ROWS 4096
#define D_DIM  768

#define BT 256             // block tile: 256x256 (traffic = 2*(4096/BT)*12.6MB)
#define BK 64              // K-slab: 64 bf16 = 128 B per row = 8 x 16B chunks
#define NKT (D_DIM / BK)   // 12 K-slabs
#define NBLK (B_ROWS / BT) // 16 block tiles per dim
#define GRID_TILES (NBLK * NBLK)   // 256 blocks = 1 per CU

typedef __attribute__((ext_vector_type(8)))  short bf16x8;   // MFMA A/B frag (4 VGPRs)
typedef __attribute__((ext_vector_type(16))) float f32x16;   // 32x32 MFMA C/D frag
typedef __attribute__((ext_vector_type(4)))  float f32x4;

__device__ __forceinline__ unsigned short f32_to_bf16(float x) {
    unsigned int u = __float_as_uint(x);   // RNE; inputs finite
    return (unsigned short)((u + 0x7fffu + ((u >> 16) & 1u)) >> 16);
}

// async global->LDS, 16 B per lane; LDS dest = wave-uniform base + lane*16.
__device__ __forceinline__ void async_copy16(const unsigned short* g, unsigned short* l) {
    __builtin_amdgcn_global_load_lds(
        (const __attribute__((address_space(1))) unsigned int*)g,
        (__attribute__((address_space(3))) unsigned int*)l,
        16, 0, 0);
}

// K1: per-row stats + fp32->bf16 (row-major copy). One WAVE per row.
__global__ void __launch_bounds__(256) rowstats_kernel(
    const float* __restrict__ P, const float* __restrict__ T,
    unsigned short* __restrict__ Pb, unsigned short* __restrict__ Tb,
    float* __restrict__ p_sq, float* __restrict__ t_sq,
    float* __restrict__ diagl, float* __restrict__ magr,
    float* __restrict__ rowsum, unsigned int* __restrict__ counter)
{
    if (blockIdx.x == 0 && threadIdx.x == 0) *counter = 0u;
    const int wave = threadIdx.x >> 6, lane = threadIdx.x & 63;
    const int i = blockIdx.x * 4 + wave;
    const f32x4* prow = (const f32x4*)(P + (size_t)i * D_DIM);
    const f32x4* trow = (const f32x4*)(T + (size_t)i * D_DIM);
    ushort4* pbrow = (ushort4*)(Pb + (size_t)i * D_DIM);
    ushort4* tbrow = (ushort4*)(Tb + (size_t)i * D_DIM);

    float psq = 0.f, tsq = 0.f, cr = 0.f, l1 = 0.f, tm = 0.f;
    #pragma unroll
    for (int u = 0; u < 3; ++u) {         // 192 float4 per row / 64 lanes
        const int c4 = u * 64 + lane;
        f32x4 p = prow[c4], t = trow[c4];
        #pragma unroll
        for (int k = 0; k < 4; ++k) {
            psq += p[k] * p[k]; tsq += t[k] * t[k]; cr += p[k] * t[k];
            l1 += fabsf(p[k] - t[k]); tm += fabsf(t[k]);
        }
        pbrow[c4] = make_ushort4(f32_to_bf16(p[0]), f32_to_bf16(p[1]),
                                 f32_to_bf16(p[2]), f32_to_bf16(p[3]));
        tbrow[c4] = make_ushort4(f32_to_bf16(t[0]), f32_to_bf16(t[1]),
                                 f32_to_bf16(t[2]), f32_to_bf16(t[3]));
    }
    #pragma unroll
    for (int m = 1; m < 64; m <<= 1) {
        psq += __shfl_xor(psq, m, 64);
        tsq += __shfl_xor(tsq, m, 64);
        cr  += __shfl_xor(cr,  m, 64);
        l1  += __shfl_xor(l1,  m, 64);
        tm  += __shfl_xor(tm,  m, 64);
    }
    if (lane == 0) {
        p_sq[i] = psq;
        t_sq[i] = tsq;
        float sq = fmaxf(psq + tsq - 2.0f * cr, 0.0f);
        diagl[i] = -sqrtf(sq) * 10.0f;    // logit_ii = -dist/0.1 (LSE shift)
        magr[i]  = l1 / tm;
        rowsum[i] = 0.0f;
    }
}

// K2: 256x256-tile bf16-MFMA cross GEMM + shifted-exp row-sum + fused finalize.
//
// R2/R7 post-mortem: both structures pinned at ~6.7 TB/s of operand refetch
// (fabric/LLC ceiling for cross-XCD reads). Traffic = 2*(4096/BT)*12.6MB,
// so BT 128->256 halves it (402->201 MB). 512 threads, 8 waves of 64x128
// (2x4 of mfma_32x32x16, 128 acc regs). Staging via global_load_lds (the
// only pattern the allocator never spills: R2 vs R4/R5/R6 evidence).
// XCD mapping: j-window = f(flat&7) -> each XCD keeps a fixed 786 KB
// B-strip in its L2 and streams A through it.
// LDS chunk-XOR swizzle (slot = chunk ^ row&7): 0 conflicts (R2-R7).
__global__ void __launch_bounds__(512, 2) lse_gemm_kernel(
    const unsigned short* __restrict__ Pb, const unsigned short* __restrict__ Tb,
    const float* __restrict__ p_sq, const float* __restrict__ t_sq,
    const float* __restrict__ diagl, const float* __restrict__ magr,
    float* __restrict__ rowsum, unsigned int* __restrict__ counter,
    float* __restrict__ out)
{
    __shared__ __align__(16) unsigned short As[BT * BK];  // 32 KB
    __shared__ __align__(16) unsigned short Bs[BT * BK];  // 32 KB

    const int tid  = threadIdx.x;
    const int lane = tid & 63;
    const int wave = tid >> 6;          // 0..7
    const int wm = wave >> 1;           // 0..3: 64-row band
    const int wn = wave & 1;            // 0..1: 128-col band
    const int h  = lane >> 5, l5 = lane & 31;

    // XCD-pinned mapping: xcd = flat&7 owns columns [xcd*512, xcd*512+512)
    const int flat = blockIdx.x;
    const int xcd  = flat & 7;
    const int idx  = flat >> 3;          // 0..31
    const int j0   = (xcd * 2 + (idx & 1)) * BT;   // T col-block (B-strip per XCD)
    const int i0   = (idx >> 1) * BT;              // P row-block

    // staging map (per wave w, round it in 0..3): rows it*64 + w*8 + (L>>3),
    // global chunk (L&7)^(row&7) = (L&7)^((L>>3)&7); LDS slot = lane order.
    const int lr = lane >> 3;            // 0..7
    const int lc = (lane & 7) ^ (lr & 7);
    const unsigned short* gA = Pb + (size_t)(i0 + wave * 8 + lr) * D_DIM + lc * 8;
    const unsigned short* gB = Tb + (size_t)(j0 + wave * 8 + lr) * D_DIM + lc * 8;
    unsigned short* lA = &As[(wave * 8) * BK];     // +64 rows per round
    unsigned short* lB = &Bs[(wave * 8) * BK];

    f32x16 acc[2][4];
    #pragma unroll
    for (int a = 0; a < 2; ++a)
        #pragma unroll
        for (int b = 0; b < 4; ++b)
            #pragma unroll
            for (int e = 0; e < 16; ++e) acc[a][b][e] = 0.f;

    const char* Ab = (const char*)As;
    const char* Bb = (const char*)Bs;
    // ds_read frag addr: row*128 + ((k8 ^ (row&7))<<4); row = base + l5
    const int arow0 = wm * 64 + l5;          // A rows for m-tile 0 (tile1: +32)
    const int brow0 = wn * 128 + l5;         // B rows for n-tile 0 (+32*nt)

    for (int kt = 0; kt < NKT; ++kt) {
        if (kt) __syncthreads();
        const int ko = kt * BK;
        #pragma unroll
        for (int it = 0; it < 4; ++it) {     // 4 rounds x 512 thr x 16B = 32KB each
            async_copy16(gA + (size_t)it * 64 * D_DIM + ko, lA + it * 64 * BK);
            async_copy16(gB + (size_t)it * 64 * D_DIM + ko, lB + it * 64 * BK);
        }
        __syncthreads();                     // drain: tile ready

        #pragma unroll
        for (int ks = 0; ks < 4; ++ks) {     // 4 steps of K=16 (2 chunks each)
            const int k8 = ks * 2 + h;       // this half-wave's chunk pair base
            bf16x8 a[2], b[4];
            #pragma unroll
            for (int mt = 0; mt < 2; ++mt) {
                const int r = arow0 + mt * 32;
                a[mt] = *(const bf16x8*)(Ab + r * 128 + ((k8 ^ (r & 7)) << 4));
            }
            #pragma unroll
            for (int nt = 0; nt < 4; ++nt) {
                const int r = brow0 + nt * 32;
                b[nt] = *(const bf16x8*)(Bb + r * 128 + ((k8 ^ (r & 7)) << 4));
            }
            #pragma unroll
            for (int mt = 0; mt < 2; ++mt)
                #pragma unroll
                for (int nt = 0; nt < 4; ++nt)
                    acc[mt][nt] = __builtin_amdgcn_mfma_f32_32x32x16_bf16(
                        a[mt], b[nt], acc[mt][nt], 0, 0, 0);
        }
    }

    // Epilogue: 32x32 C/D layout (m74/m101): col=lane&31,
    // row=(reg&3)+8*(reg>>2)+4*(lane>>5). term = exp2((logit-logit_ii)*log2e).
    const float NT_LOG2E = -14.4269504089f;   // -(1/TEMP)*log2(e)
    const float LOG2E    = 1.44269504089f;
    const float pv = p_sq[i0 + wm * 64 + lane];   // wave's 64 rows across lanes
    const float dv = diagl[i0 + wm * 64 + lane];
    float tq[4];
    #pragma unroll
    for (int nt = 0; nt < 4; ++nt)
        tq[nt] = t_sq[j0 + wn * 128 + nt * 32 + l5];

    #pragma unroll
    for (int mt = 0; mt < 2; ++mt) {
        #pragma unroll
        for (int r = 0; r < 16; ++r) {
            const int rr = mt * 32 + (r & 3) + 8 * (r >> 2) + 4 * h;  // 0..63
            const float psq = __shfl(pv, rr, 64);
            const float c0  = -__shfl(dv, rr, 64) * LOG2E;
            float sm = 0.f;
            #pragma unroll
            for (int nt = 0; nt < 4; ++nt) {
                float c  = acc[mt][nt][r];
                float sq = fmaxf(fmaf(-2.0f, c, psq + tq[nt]), 0.0f);
                sm += exp2f(fmaf(sqrtf(sq), NT_LOG2E, c0));
            }
            #pragma unroll
            for (int m = 1; m < 32; m <<= 1) sm += __shfl_xor(sm, m, 64);
            if (l5 == 0) atomicAdd(&rowsum[i0 + wm * 64 + rr], sm);
        }
    }

    // Fused finalize: last block reduces rowsum -> 3 scalars (rowsum only
    // touched by device-scope atomics; reads via atomicAdd(p,0) coherent).
    __threadfence();
    __shared__ unsigned int lastflag;
    if (tid == 0) {
        unsigned int old = atomicAdd(counter, 1u);
        lastflag = (old == (unsigned)(GRID_TILES - 1)) ? 1u : 0u;
    }
    __syncthreads();
    if (lastflag) {
        double sc = 0.0, smg = 0.0;
        for (int i = tid; i < B_ROWS; i += 512) {
            float rs = atomicAdd(&rowsum[i], 0.0f);
            sc += (double)logf(rs);
            smg += (double)magr[i];
        }
        #pragma unroll
        for (int m = 1; m < 64; m <<= 1) {
            sc  += __shfl_xor(sc,  m, 64);
            smg += __shfl_xor(smg, m, 64);
        }
        __shared__ double red2[8][2];
        if ((tid & 63) == 0) { red2[tid >> 6][0] = sc; red2[tid >> 6][1] = smg; }
        __syncthreads();
        if (tid == 0) {
            sc = 0.0; smg = 0.0;
            #pragma unroll
            for (int wv = 0; wv < 8; ++wv) { sc += red2[wv][0]; smg += red2[wv][1]; }
            double lc = sc / (double)B_ROWS;
            double lm = smg / (double)B_ROWS;
            out[0] = (float)(0.5 * lc + 0.5 * lm);  // LOSS_SCALE=1, LAMBD=0.5
            out[1] = (float)lc;
            out[2] = (float)lm;
        }
    }
}

extern "C" void kernel_launch(void* const* d_in, const int* in_sizes, int n_in,
                              void* d_out, int out_size, void* d_ws, size_t ws_size,
                              hipStream_t stream) {
    const float* P = (const float*)d_in[0];   // predicted [4096,768] fp32
    const float* T = (const float*)d_in[1];   // target    [4096,768] fp32
    float* out = (float*)d_out;               // 3 fp32 scalars

    char* ws = (char*)d_ws;
    float* rowsum = (float*)ws;               ws += B_ROWS * sizeof(float);
    float* p_sq   = (float*)ws;               ws += B_ROWS * sizeof(float);
    float* t_sq   = (float*)ws;               ws += B_ROWS * sizeof(float);
    float* diagl  = (float*)ws;               ws += B_ROWS * sizeof(float);
    float* magr   = (float*)ws;               ws += B_ROWS * sizeof(float);
    unsigned int* counter = (unsigned int*)ws; ws += 16;  // keep 16B align
    unsigned short* Pb = (unsigned short*)ws; ws += (size_t)B_ROWS * D_DIM * 2;
    unsigned short* Tb = (unsigned short*)ws;

    rowstats_kernel<<<B_ROWS / 4, 256, 0, stream>>>(
        P, T, Pb, Tb, p_sq, t_sq, diagl, magr, rowsum, counter);
    lse_gemm_kernel<<<GRID_TILES, 512, 0, stream>>>(
        Pb, Tb, p_sq, t_sq, diagl, magr, rowsum, counter, out);
}